// Round 9
// baseline (702.652 us; speedup 1.0000x reference)
//
#include <hip/hip_runtime.h>
#include <hip/hip_bf16.h>
#include <stdint.h>

// SplineCouplingLayer on MI355X — round 9 (= round 7 kernel, resubmitted;
// r7 and r8 benches never ran: GPU acquisition timeouts).
// r6 -> r7: revert the (regressing) 2-phase pipeline; back to r5's proven
// serial stage->sync->compute loop but with BK=32 + single 32KB staging
// buffer and a 64-row epilogue pf (34KB LDS total vs 68KB) -> 4 blocks/CU
// (was 2; occupancy was the r5 limiter: drains/epilogue couldn't overlap).
// Keep r6's bijective XCD swizzle (proven: FETCH 225->66MB).
// Softmax expf -> __expf (absmax evidence r3-r6: bit-identical under epilogue
// math changes -> worst element is a GEMM-side bin flip, not epilogue ulp).
// d_ws: hid_hi 16MB | hid_lo 16MB | w2t_hi 852KB | w2t_lo 852KB.

#define B_ROWS 32768
#define DDIM   128
#define HDIM   256
#define NPACK  1664        // 13 blocks * 128 cols (5 de * 25 params + 3 dead)
#define LOSCALE 2048.0f
#define INV_LOSCALE (1.0f / 2048.0f)

using f32x4 = __attribute__((ext_vector_type(4))) float;
using f16x8 = __attribute__((ext_vector_type(8))) _Float16;
using f16x4 = __attribute__((ext_vector_type(4))) _Float16;

__device__ __forceinline__ void gl_lds16(const void* g, void* l) {
    __builtin_amdgcn_global_load_lds(
        (__attribute__((address_space(1))) void*)(void*)g,
        (__attribute__((address_space(3))) void*)l, 16, 0, 0);
}

__device__ __forceinline__ float rcpf(float x) { return __builtin_amdgcn_rcpf(x); }

__device__ __forceinline__ float softplus_fast(float z) {
    return fmaxf(z, 0.0f) + __logf(1.0f + __expf(-fabsf(z)));
}

// ---- RQS spline on one (row, even-dim): P[0..7]=u_w, P[8..15]=u_h, P[16..24]=u_d
__device__ __forceinline__ void rqs(const float* P, float xv, float& o, float& l) {
    float ew[8], vw[8], edw[9];
    float mw = P[0];
    #pragma unroll
    for (int j = 1; j < 8; ++j) mw = fmaxf(mw, P[j]);
    float sw = 0.0f;
    #pragma unroll
    for (int j = 0; j < 8; ++j) { ew[j] = __expf(P[j] - mw); sw += ew[j]; }
    float rsw = rcpf(sw);
    float cum = 0.0f;
    edw[0] = -3.0f;
    #pragma unroll
    for (int j = 0; j < 8; ++j) {
        vw[j] = 0.001f + 0.992f * (ew[j] * rsw);
        cum += vw[j];
        edw[j + 1] = (cum - 0.5f) * 6.0f;
    }
    edw[8] += 1e-6f;

    float eh[8], vh[8], edh[9];
    float mh = P[8];
    #pragma unroll
    for (int j = 1; j < 8; ++j) mh = fmaxf(mh, P[8 + j]);
    float sh = 0.0f;
    #pragma unroll
    for (int j = 0; j < 8; ++j) { eh[j] = __expf(P[8 + j] - mh); sh += eh[j]; }
    float rsh = rcpf(sh);
    float cumh = 0.0f;
    edh[0] = -3.0f;
    #pragma unroll
    for (int j = 0; j < 8; ++j) {
        vh[j] = 0.001f + 0.992f * (eh[j] * rsh);
        cumh += vh[j];
        edh[j + 1] = (cumh - 0.5f) * 6.0f;
    }

    float dk[9];
    #pragma unroll
    for (int j = 0; j < 9; ++j) dk[j] = softplus_fast(P[16 + j]) + 0.001f;

    int idx = -1;
    #pragma unroll
    for (int j = 0; j < 9; ++j) idx += (xv >= edw[j]) ? 1 : 0;
    idx = min(max(idx, 0), 7);

    float cw = edw[0], ww = vw[0], ch = edh[0], hh = vh[0], di = dk[0], di1 = dk[1];
    #pragma unroll
    for (int j = 0; j < 8; ++j) {
        bool sel = (idx == j);
        cw  = sel ? edw[j]    : cw;
        ww  = sel ? vw[j]     : ww;
        ch  = sel ? edh[j]    : ch;
        hh  = sel ? vh[j]     : hh;
        di  = sel ? dk[j]     : di;
        di1 = sel ? dk[j + 1] : di1;
    }
    di  = fminf(fmaxf(di,  0.001f), 1000.0f);
    di1 = fminf(fmaxf(di1, 0.001f), 1000.0f);

    float rww   = rcpf(ww);
    float delta = hh * rww;
    float theta = fminf(fmaxf((xv - cw) * rww, 0.0f), 1.0f);
    float t1m   = theta * (1.0f - theta);
    float th2   = theta * theta;
    float omt   = 1.0f - theta;
    float num_term = di1 * th2 + delta * t1m;
    float den      = fmaxf(delta + (di + di1 - 2.0f * delta) * t1m, 1e-6f);
    float rden     = rcpf(den);
    float sp       = ch + delta * num_term * rden * ww;
    float dn       = (delta * delta) * (di1 * th2 + 2.0f * delta * t1m + di * (omt * omt));
    float ld       = __logf(fmaxf(dn * rden * rden, 1e-12f));

    bool inr = (xv >= -3.0f) && (xv <= 3.0f);
    o = inr ? sp : xv;
    l = inr ? ld : 0.0f;
}

// -------------------- K1: hidden = relu(x_odd @ W1_odd + b1) -> fp16 hi/lo
// Register-blocked (8 rows x 4 cols / thread); XCD-swizzled so written rows
// stay in the XCD that k2 will read them from.
__global__ __launch_bounds__(256, 4) void k1_hidden(const float* __restrict__ x,
                                                    const float* __restrict__ W1,
                                                    const float* __restrict__ b1,
                                                    _Float16* __restrict__ hid_hi,
                                                    _Float16* __restrict__ hid_lo,
                                                    float* __restrict__ out,
                                                    float* __restrict__ logdet) {
    __shared__ float xodT[64][36];                 // [k][row], pitch 36
    const int t  = threadIdx.x;
    const int wg = blockIdx.x;                     // 1024 = 8 * 128
    const int lb = (wg & 7) * 128 + (wg >> 3);     // bijective XCD chunking
    const int rb = lb * 32;
    const int cg = t & 63;                         // col group: cols cg*4..+3
    const int rg = t >> 6;                         // row group (wave-uniform)
    #pragma unroll
    for (int u = 0; u < 8; ++u) {
        int idx = u * 256 + t;
        int r = idx >> 6, k = idx & 63;
        float2 v = *(const float2*)&x[(rb + r) * DDIM + 2 * k];   // coalesced 8B
        xodT[k][r] = v.y;                                          // odd element
        *(float2*)&out[(rb + r) * DDIM + 2 * k] = v;               // pass-through
    }
    if (t < 32) logdet[rb + t] = 0.0f;
    __syncthreads();

    float acc[8][4];
    #pragma unroll
    for (int r = 0; r < 8; ++r)
        #pragma unroll
        for (int c = 0; c < 4; ++c) acc[r][c] = 0.0f;

    #pragma unroll 4
    for (int k = 0; k < 64; ++k) {
        float4 w  = *(const float4*)&W1[(2 * k + 1) * HDIM + cg * 4];  // coalesced
        float4 xa = *(const float4*)&xodT[k][rg * 8];                  // broadcast
        float4 xb = *(const float4*)&xodT[k][rg * 8 + 4];              // broadcast
        float xr[8] = {xa.x, xa.y, xa.z, xa.w, xb.x, xb.y, xb.z, xb.w};
        float wc[4] = {w.x, w.y, w.z, w.w};
        #pragma unroll
        for (int r = 0; r < 8; ++r)
            #pragma unroll
            for (int c = 0; c < 4; ++c) acc[r][c] += xr[r] * wc[c];
    }

    float4 bias = *(const float4*)&b1[cg * 4];
    float bc[4] = {bias.x, bias.y, bias.z, bias.w};
    #pragma unroll
    for (int r = 0; r < 8; ++r) {
        int row = rb + rg * 8 + r;
        f16x4 vh, vl;
        #pragma unroll
        for (int c = 0; c < 4; ++c) {
            float h = fmaxf(acc[r][c] + bc[c], 0.0f);
            _Float16 hi = (_Float16)h;
            vh[c] = hi;
            vl[c] = (_Float16)((h - (float)hi) * LOSCALE);
        }
        *(f16x4*)&hid_hi[(size_t)row * HDIM + cg * 4] = vh;   // 8B coalesced
        *(f16x4*)&hid_lo[(size_t)row * HDIM + cg * 4] = vl;
    }
}

// -------------------- K3: W2 -> packed transposed fp16 hi/lo [NPACK][256]
__global__ __launch_bounds__(256) void k3_w2split(const float* __restrict__ W2,
                                                  _Float16* __restrict__ w2t_hi,
                                                  _Float16* __restrict__ w2t_lo) {
    int tid = blockIdx.x * 256 + threadIdx.x;     // 53248 = NPACK*32
    int c  = tid >> 5;                            // packed col 0..1663
    int kc = tid & 31;                            // k-chunk of 8
    int bx = c >> 7;
    int cb = c & 127;
    int de = bx * 5 + cb / 25;
    int j  = cb % 25;
    bool valid = (cb < 125) && (de < 64);
    f16x8 vh, vl;
    #pragma unroll
    for (int i = 0; i < 8; ++i) {
        float v = valid ? W2[(size_t)(kc * 8 + i) * 3200 + 50 * de + j] : 0.0f;
        _Float16 h = (_Float16)v;
        vh[i] = h;
        vl[i] = (_Float16)((v - (float)h) * LOSCALE);
    }
    *(f16x8*)&w2t_hi[(size_t)c * HDIM + kc * 8] = vh;
    *(f16x8*)&w2t_lo[(size_t)c * HDIM + kc * 8] = vl;
}

// -------------------- K2: MFMA GEMM (BK=32, serial, 34KB LDS) + spline
// LDS staging: A rows 0..127 at 0 (16KB), B at +16384 (16KB). Row = 128B =
// 8 slots of 16B; slot s of row r holds chunk c = s ^ (r&7); c<4 -> hi
// k-chunk c, c>=4 -> lo k-chunk c-4. Epilogue reuses LDS as pf[64][133].
__global__ __launch_bounds__(256, 4) void k2_mfma(
        const float* __restrict__ x,
        const _Float16* __restrict__ hid_hi, const _Float16* __restrict__ hid_lo,
        const _Float16* __restrict__ w2t_hi, const _Float16* __restrict__ w2t_lo,
        const float* __restrict__ b2,
        float* __restrict__ out, float* __restrict__ logdet) {
    __shared__ __align__(16) char smem[64 * 133 * 4];   // 34048 B (> 32768 staging)
    const int t    = threadIdx.x;
    const int lane = t & 63;
    const int wave = t >> 6;
    const int m0   = (wave & 1) * 64;
    const int n0   = (wave >> 1) * 64;

    // bijective XCD swizzle: 3328 = 8*416 blocks; each XCD owns 32 y-panels
    const int wg = blockIdx.y * 13 + blockIdx.x;
    const int lb = (wg & 7) * 416 + (wg >> 3);
    const int bx = lb % 13;
    const int by = lb / 13;
    const int row0 = by * 128;
    const int col0 = bx * 128;

    f32x4 acc[4][4], acc2[4][4];
    #pragma unroll
    for (int i = 0; i < 4; ++i)
        #pragma unroll
        for (int j = 0; j < 4; ++j) {
            acc[i][j]  = (f32x4){0.f, 0.f, 0.f, 0.f};
            acc2[i][j] = (f32x4){0.f, 0.f, 0.f, 0.f};
        }

    for (int ks = 0; ks < 8; ++ks) {
        __syncthreads();                          // prev step's reads done
        // stage 32KB: 32 wave-groups of 1KB (16 A + 16 B) over 4 waves.
        #pragma unroll
        for (int cc = 0; cc < 8; ++cc) {
            int g  = cc * 4 + wave;               // 0..31, wave-uniform
            int gg = g & 15;
            int rt = gg * 8 + (lane >> 3);        // tile row/col 0..127
            int c  = (lane & 7) ^ (rt & 7);       // logical chunk 0..7
            int ke = ks * 32 + (c & 3) * 8;       // element offset in K
            char* ldsb = smem + ((g >> 4) << 14) + gg * 1024;   // linear dest
            const _Float16* src;
            if (g < 16) src = ((c & 4) ? hid_lo : hid_hi) + (size_t)(row0 + rt) * HDIM + ke;
            else        src = ((c & 4) ? w2t_lo : w2t_hi) + (size_t)(col0 + rt) * HDIM + ke;
            gl_lds16(src, ldsb);
        }
        __syncthreads();                          // vmcnt(0) drained by compiler

        const int kc = lane >> 4;                 // k-chunk 0..3 this lane
        f16x8 ah[4], al[4], bh[4], bl[4];
        #pragma unroll
        for (int i = 0; i < 4; ++i) {
            int ra = m0 + i * 16 + (lane & 15);
            ah[i] = *(const f16x8*)(smem + ra * 128 + ((kc ^ (ra & 7)) << 4));
            al[i] = *(const f16x8*)(smem + ra * 128 + (((kc | 4) ^ (ra & 7)) << 4));
            int rb_ = n0 + i * 16 + (lane & 15);
            bh[i] = *(const f16x8*)(smem + 16384 + rb_ * 128 + ((kc ^ (rb_ & 7)) << 4));
            bl[i] = *(const f16x8*)(smem + 16384 + rb_ * 128 + (((kc | 4) ^ (rb_ & 7)) << 4));
        }
        #pragma unroll
        for (int mi = 0; mi < 4; ++mi)
            #pragma unroll
            for (int ni = 0; ni < 4; ++ni) {
                acc[mi][ni]  = __builtin_amdgcn_mfma_f32_16x16x32_f16(ah[mi], bh[ni], acc[mi][ni],  0, 0, 0);
                acc2[mi][ni] = __builtin_amdgcn_mfma_f32_16x16x32_f16(al[mi], bh[ni], acc2[mi][ni], 0, 0, 0);
                acc2[mi][ni] = __builtin_amdgcn_mfma_f32_16x16x32_f16(ah[mi], bl[ni], acc2[mi][ni], 0, 0, 0);
            }
    }

    // ---- epilogue in two 64-row halves: pf[64][133] (34KB), then splines
    float* pf = (float*)smem;
    #pragma unroll
    for (int h = 0; h < 2; ++h) {
        __syncthreads();                          // staging / prev half done
        if ((wave & 1) == h) {                    // waves owning rows h*64..+63
            #pragma unroll
            for (int mi = 0; mi < 4; ++mi)
                #pragma unroll
                for (int ni = 0; ni < 4; ++ni)
                    #pragma unroll
                    for (int e = 0; e < 4; ++e) {
                        int rl = mi * 16 + (lane >> 4) * 4 + e;        // 0..63
                        int cl = n0 + ni * 16 + (lane & 15);
                        pf[rl * 133 + cl] = acc[mi][ni][e] + acc2[mi][ni][e] * INV_LOSCALE;
                    }
        }
        __syncthreads();

        const int r    = t & 63;
        const int rowg = row0 + h * 64 + r;
        float ldsum = 0.0f;
        // pass 0: dl = t>>6 (0..3); pass 1: dl = 4, threads t<64 only
        {
            int dl = t >> 6;
            int de = bx * 5 + dl;
            float xv = x[(size_t)rowg * DDIM + 2 * de];
            float P[25];
            #pragma unroll
            for (int j = 0; j < 25; ++j)
                P[j] = pf[r * 133 + dl * 25 + j] + b2[50 * de + j];
            float o, l;
            rqs(P, xv, o, l);
            out[(size_t)rowg * DDIM + 2 * de] = o;
            ldsum += l;
        }
        if (t < 64) {
            int de = bx * 5 + 4;
            if (de < 64) {                        // bx=12 has only 4 de
                float xv = x[(size_t)rowg * DDIM + 2 * de];
                float P[25];
                #pragma unroll
                for (int j = 0; j < 25; ++j)
                    P[j] = pf[r * 133 + 4 * 25 + j] + b2[50 * de + j];
                float o, l;
                rqs(P, xv, o, l);
                out[(size_t)rowg * DDIM + 2 * de] = o;
                ldsum += l;
            }
        }
        atomicAdd(&logdet[rowg], ldsum);
    }
}

extern "C" void kernel_launch(void* const* d_in, const int* in_sizes, int n_in,
                              void* d_out, int out_size, void* d_ws, size_t ws_size,
                              hipStream_t stream) {
    const float* x  = (const float*)d_in[0];
    // d_in[1] = mask — structure (d%2) hardcoded
    const float* W1 = (const float*)d_in[2];
    const float* b1 = (const float*)d_in[3];
    const float* W2 = (const float*)d_in[4];
    const float* b2 = (const float*)d_in[5];

    float* out    = (float*)d_out;                          // [B, D]
    float* logdet = (float*)d_out + (size_t)B_ROWS * DDIM;  // [B]

    _Float16* hid_hi = (_Float16*)d_ws;                     // 16 MB
    _Float16* hid_lo = hid_hi + (size_t)B_ROWS * HDIM;      // 16 MB
    _Float16* w2t_hi = hid_lo + (size_t)B_ROWS * HDIM;      // 852 KB
    _Float16* w2t_lo = w2t_hi + (size_t)NPACK * HDIM;       // 852 KB

    k3_w2split<<<dim3(NPACK * 32 / 256), dim3(256), 0, stream>>>(W2, w2t_hi, w2t_lo);
    k1_hidden <<<dim3(B_ROWS / 32),      dim3(256), 0, stream>>>(x, W1, b1, hid_hi, hid_lo, out, logdet);
    k2_mfma   <<<dim3(13, B_ROWS / 128), dim3(256), 0, stream>>>(
        x, hid_hi, hid_lo, w2t_hi, w2t_lo, b2, out, logdet);
}

// Round 11
// 195.907 us; speedup vs baseline: 3.5867x; 3.5867x over previous
//
#include <hip/hip_runtime.h>
#include <hip/hip_bf16.h>
#include <stdint.h>

// SplineCouplingLayer on MI355X — round 11 (= round 10 kernel resubmitted;
// r10 bench never ran: GPU acquisition timeout — 3rd timeout this session).
// r9 post-mortem: __launch_bounds__(256,4) halved the VGPR budget to 128 <
// the ~180 this kernel needs -> accumulator spill to scratch (VGPR 116->64,
// FETCH+WRITE 2.7GB, k2 624us). Occupancy is VGPR-limited at 2 blocks/CU —
// not LDS-limited; r7's premise was wrong.
// r10 = r5's proven k2 (127us, BK=64 serial loop, launch_bounds(256,2))
// + three individually-validated deltas:
//   (1) bijective XCD swizzle (r6: FETCH 225->66MB),
//   (2) __expf softmaxes (r9: absmax bit-identical 0.7695312),
//   (3) pf[64][133] two-half epilogue (LDS 68->64KB).
// d_ws: hid_hi 16MB | hid_lo 16MB | w2t_hi 852KB | w2t_lo 852KB.

#define B_ROWS 32768
#define DDIM   128
#define HDIM   256
#define NPACK  1664        // 13 blocks * 128 cols (5 de * 25 params + 3 dead)
#define LOSCALE 2048.0f
#define INV_LOSCALE (1.0f / 2048.0f)

using f32x4 = __attribute__((ext_vector_type(4))) float;
using f16x8 = __attribute__((ext_vector_type(8))) _Float16;
using f16x4 = __attribute__((ext_vector_type(4))) _Float16;

__device__ __forceinline__ void gl_lds16(const void* g, void* l) {
    __builtin_amdgcn_global_load_lds(
        (__attribute__((address_space(1))) void*)(void*)g,
        (__attribute__((address_space(3))) void*)l, 16, 0, 0);
}

__device__ __forceinline__ float rcpf(float x) { return __builtin_amdgcn_rcpf(x); }

__device__ __forceinline__ float softplus_fast(float z) {
    return fmaxf(z, 0.0f) + __logf(1.0f + __expf(-fabsf(z)));
}

// ---- RQS spline on one (row, even-dim): P[0..7]=u_w, P[8..15]=u_h, P[16..24]=u_d
__device__ __forceinline__ void rqs(const float* P, float xv, float& o, float& l) {
    float ew[8], vw[8], edw[9];
    float mw = P[0];
    #pragma unroll
    for (int j = 1; j < 8; ++j) mw = fmaxf(mw, P[j]);
    float sw = 0.0f;
    #pragma unroll
    for (int j = 0; j < 8; ++j) { ew[j] = __expf(P[j] - mw); sw += ew[j]; }
    float rsw = rcpf(sw);
    float cum = 0.0f;
    edw[0] = -3.0f;
    #pragma unroll
    for (int j = 0; j < 8; ++j) {
        vw[j] = 0.001f + 0.992f * (ew[j] * rsw);
        cum += vw[j];
        edw[j + 1] = (cum - 0.5f) * 6.0f;
    }
    edw[8] += 1e-6f;

    float eh[8], vh[8], edh[9];
    float mh = P[8];
    #pragma unroll
    for (int j = 1; j < 8; ++j) mh = fmaxf(mh, P[8 + j]);
    float sh = 0.0f;
    #pragma unroll
    for (int j = 0; j < 8; ++j) { eh[j] = __expf(P[8 + j] - mh); sh += eh[j]; }
    float rsh = rcpf(sh);
    float cumh = 0.0f;
    edh[0] = -3.0f;
    #pragma unroll
    for (int j = 0; j < 8; ++j) {
        vh[j] = 0.001f + 0.992f * (eh[j] * rsh);
        cumh += vh[j];
        edh[j + 1] = (cumh - 0.5f) * 6.0f;
    }

    float dk[9];
    #pragma unroll
    for (int j = 0; j < 9; ++j) dk[j] = softplus_fast(P[16 + j]) + 0.001f;

    int idx = -1;
    #pragma unroll
    for (int j = 0; j < 9; ++j) idx += (xv >= edw[j]) ? 1 : 0;
    idx = min(max(idx, 0), 7);

    float cw = edw[0], ww = vw[0], ch = edh[0], hh = vh[0], di = dk[0], di1 = dk[1];
    #pragma unroll
    for (int j = 0; j < 8; ++j) {
        bool sel = (idx == j);
        cw  = sel ? edw[j]    : cw;
        ww  = sel ? vw[j]     : ww;
        ch  = sel ? edh[j]    : ch;
        hh  = sel ? vh[j]     : hh;
        di  = sel ? dk[j]     : di;
        di1 = sel ? dk[j + 1] : di1;
    }
    di  = fminf(fmaxf(di,  0.001f), 1000.0f);
    di1 = fminf(fmaxf(di1, 0.001f), 1000.0f);

    float rww   = rcpf(ww);
    float delta = hh * rww;
    float theta = fminf(fmaxf((xv - cw) * rww, 0.0f), 1.0f);
    float t1m   = theta * (1.0f - theta);
    float th2   = theta * theta;
    float omt   = 1.0f - theta;
    float num_term = di1 * th2 + delta * t1m;
    float den      = fmaxf(delta + (di + di1 - 2.0f * delta) * t1m, 1e-6f);
    float rden     = rcpf(den);
    float sp       = ch + delta * num_term * rden * ww;
    float dn       = (delta * delta) * (di1 * th2 + 2.0f * delta * t1m + di * (omt * omt));
    float ld       = __logf(fmaxf(dn * rden * rden, 1e-12f));

    bool inr = (xv >= -3.0f) && (xv <= 3.0f);
    o = inr ? sp : xv;
    l = inr ? ld : 0.0f;
}

// -------------------- K1: hidden = relu(x_odd @ W1_odd + b1) -> fp16 hi/lo
// Register-blocked (8 rows x 4 cols / thread); XCD-swizzled so written rows
// stay in the XCD that k2 will read them from.
__global__ __launch_bounds__(256, 4) void k1_hidden(const float* __restrict__ x,
                                                    const float* __restrict__ W1,
                                                    const float* __restrict__ b1,
                                                    _Float16* __restrict__ hid_hi,
                                                    _Float16* __restrict__ hid_lo,
                                                    float* __restrict__ out,
                                                    float* __restrict__ logdet) {
    __shared__ float xodT[64][36];                 // [k][row], pitch 36
    const int t  = threadIdx.x;
    const int wg = blockIdx.x;                     // 1024 = 8 * 128
    const int lb = (wg & 7) * 128 + (wg >> 3);     // bijective XCD chunking
    const int rb = lb * 32;
    const int cg = t & 63;                         // col group: cols cg*4..+3
    const int rg = t >> 6;                         // row group (wave-uniform)
    #pragma unroll
    for (int u = 0; u < 8; ++u) {
        int idx = u * 256 + t;
        int r = idx >> 6, k = idx & 63;
        float2 v = *(const float2*)&x[(rb + r) * DDIM + 2 * k];   // coalesced 8B
        xodT[k][r] = v.y;                                          // odd element
        *(float2*)&out[(rb + r) * DDIM + 2 * k] = v;               // pass-through
    }
    if (t < 32) logdet[rb + t] = 0.0f;
    __syncthreads();

    float acc[8][4];
    #pragma unroll
    for (int r = 0; r < 8; ++r)
        #pragma unroll
        for (int c = 0; c < 4; ++c) acc[r][c] = 0.0f;

    #pragma unroll 4
    for (int k = 0; k < 64; ++k) {
        float4 w  = *(const float4*)&W1[(2 * k + 1) * HDIM + cg * 4];  // coalesced
        float4 xa = *(const float4*)&xodT[k][rg * 8];                  // broadcast
        float4 xb = *(const float4*)&xodT[k][rg * 8 + 4];              // broadcast
        float xr[8] = {xa.x, xa.y, xa.z, xa.w, xb.x, xb.y, xb.z, xb.w};
        float wc[4] = {w.x, w.y, w.z, w.w};
        #pragma unroll
        for (int r = 0; r < 8; ++r)
            #pragma unroll
            for (int c = 0; c < 4; ++c) acc[r][c] += xr[r] * wc[c];
    }

    float4 bias = *(const float4*)&b1[cg * 4];
    float bc[4] = {bias.x, bias.y, bias.z, bias.w};
    #pragma unroll
    for (int r = 0; r < 8; ++r) {
        int row = rb + rg * 8 + r;
        f16x4 vh, vl;
        #pragma unroll
        for (int c = 0; c < 4; ++c) {
            float h = fmaxf(acc[r][c] + bc[c], 0.0f);
            _Float16 hi = (_Float16)h;
            vh[c] = hi;
            vl[c] = (_Float16)((h - (float)hi) * LOSCALE);
        }
        *(f16x4*)&hid_hi[(size_t)row * HDIM + cg * 4] = vh;   // 8B coalesced
        *(f16x4*)&hid_lo[(size_t)row * HDIM + cg * 4] = vl;
    }
}

// -------------------- K3: W2 -> packed transposed fp16 hi/lo [NPACK][256]
__global__ __launch_bounds__(256) void k3_w2split(const float* __restrict__ W2,
                                                  _Float16* __restrict__ w2t_hi,
                                                  _Float16* __restrict__ w2t_lo) {
    int tid = blockIdx.x * 256 + threadIdx.x;     // 53248 = NPACK*32
    int c  = tid >> 5;                            // packed col 0..1663
    int kc = tid & 31;                            // k-chunk of 8
    int bx = c >> 7;
    int cb = c & 127;
    int de = bx * 5 + cb / 25;
    int j  = cb % 25;
    bool valid = (cb < 125) && (de < 64);
    f16x8 vh, vl;
    #pragma unroll
    for (int i = 0; i < 8; ++i) {
        float v = valid ? W2[(size_t)(kc * 8 + i) * 3200 + 50 * de + j] : 0.0f;
        _Float16 h = (_Float16)v;
        vh[i] = h;
        vl[i] = (_Float16)((v - (float)h) * LOSCALE);
    }
    *(f16x8*)&w2t_hi[(size_t)c * HDIM + kc * 8] = vh;
    *(f16x8*)&w2t_lo[(size_t)c * HDIM + kc * 8] = vl;
}

// -------------------- K2: MFMA GEMM (128x128 tile, BK=64, r5 structure)
// Staging: Ahi@0 Alo@16K Bhi@32K Blo@48K (each 128x64 fp16 = 16KB, rows
// XOR-8 swizzled in 16B slots). Epilogue reuses LDS as pf[64][133] (two
// 64-row halves). launch_bounds(256,2): VGPR budget 256 -> no spill.
__global__ __launch_bounds__(256, 2) void k2_mfma(
        const float* __restrict__ x,
        const _Float16* __restrict__ hid_hi, const _Float16* __restrict__ hid_lo,
        const _Float16* __restrict__ w2t_hi, const _Float16* __restrict__ w2t_lo,
        const float* __restrict__ b2,
        float* __restrict__ out, float* __restrict__ logdet) {
    __shared__ __align__(16) char smem[65536];
    const int t    = threadIdx.x;
    const int lane = t & 63;
    const int wave = t >> 6;
    const int m0   = (wave & 1) * 64;
    const int n0   = (wave >> 1) * 64;

    // bijective XCD swizzle: 3328 = 8*416 blocks; each XCD owns 32 y-panels
    const int wg = blockIdx.y * 13 + blockIdx.x;
    const int lb = (wg & 7) * 416 + (wg >> 3);
    const int bx = lb % 13;
    const int by = lb / 13;
    const int row0 = by * 128;
    const int col0 = bx * 128;

    f32x4 acc[4][4], acc2[4][4];
    #pragma unroll
    for (int i = 0; i < 4; ++i)
        #pragma unroll
        for (int j = 0; j < 4; ++j) {
            acc[i][j]  = (f32x4){0.f, 0.f, 0.f, 0.f};
            acc2[i][j] = (f32x4){0.f, 0.f, 0.f, 0.f};
        }

    for (int ks = 0; ks < 4; ++ks) {
        __syncthreads();                          // prev tile fully consumed
        // stage: LDS linear; global source pre-swizzled (chunk ^= row&7)
        #pragma unroll
        for (int call = 0; call < 4; ++call) {
            int g = call * 4 + wave;              // 16 groups of 64 slots
            int s = g * 64 + lane;
            int r = s >> 3;                       // tile row 0..127
            int c = (s & 7) ^ (r & 7);            // k-chunk for this slot
            int ke = ks * 64 + c * 8;
            char* ldsb = smem + g * 1024;         // wave-uniform dest
            gl_lds16(hid_hi + (size_t)(row0 + r) * HDIM + ke, ldsb);
            gl_lds16(hid_lo + (size_t)(row0 + r) * HDIM + ke, ldsb + 16384);
            gl_lds16(w2t_hi + (size_t)(col0 + r) * HDIM + ke, ldsb + 32768);
            gl_lds16(w2t_lo + (size_t)(col0 + r) * HDIM + ke, ldsb + 49152);
        }
        __syncthreads();                          // vmcnt drained by compiler
        #pragma unroll
        for (int kk = 0; kk < 2; ++kk) {
            int kc = kk * 4 + (lane >> 4);        // k-chunk this lane reads
            int sw = ((kc ^ (lane & 7)) << 4);    // swizzled byte offset in row
            f16x8 ah[4], al[4], bh[4], bl[4];
            #pragma unroll
            for (int i = 0; i < 4; ++i) {
                int oa = (m0 + i * 16 + (lane & 15)) * 128 + sw;
                ah[i] = *(const f16x8*)(smem + oa);
                al[i] = *(const f16x8*)(smem + 16384 + oa);
                int ob = (n0 + i * 16 + (lane & 15)) * 128 + sw;
                bh[i] = *(const f16x8*)(smem + 32768 + ob);
                bl[i] = *(const f16x8*)(smem + 49152 + ob);
            }
            #pragma unroll
            for (int mi = 0; mi < 4; ++mi)
                #pragma unroll
                for (int ni = 0; ni < 4; ++ni) {
                    acc[mi][ni]  = __builtin_amdgcn_mfma_f32_16x16x32_f16(ah[mi], bh[ni], acc[mi][ni],  0, 0, 0);
                    acc2[mi][ni] = __builtin_amdgcn_mfma_f32_16x16x32_f16(al[mi], bh[ni], acc2[mi][ni], 0, 0, 0);
                    acc2[mi][ni] = __builtin_amdgcn_mfma_f32_16x16x32_f16(ah[mi], bl[ni], acc2[mi][ni], 0, 0, 0);
                }
        }
    }

    // ---- epilogue in two 64-row halves: pf[64][133] (reuses staging LDS)
    float* pf = (float*)smem;
    #pragma unroll
    for (int h = 0; h < 2; ++h) {
        __syncthreads();                          // staging / prev half done
        if ((wave & 1) == h) {                    // waves owning rows h*64..+63
            #pragma unroll
            for (int mi = 0; mi < 4; ++mi)
                #pragma unroll
                for (int ni = 0; ni < 4; ++ni)
                    #pragma unroll
                    for (int e = 0; e < 4; ++e) {
                        int rl = mi * 16 + (lane >> 4) * 4 + e;        // 0..63
                        int cl = n0 + ni * 16 + (lane & 15);
                        pf[rl * 133 + cl] = acc[mi][ni][e] + acc2[mi][ni][e] * INV_LOSCALE;
                    }
        }
        __syncthreads();

        const int r    = t & 63;
        const int rowg = row0 + h * 64 + r;
        float ldsum = 0.0f;
        // pass 0: dl = t>>6 (0..3); pass 1: dl = 4, threads t<64 only
        {
            int dl = t >> 6;
            int de = bx * 5 + dl;
            float xv = x[(size_t)rowg * DDIM + 2 * de];
            float P[25];
            #pragma unroll
            for (int j = 0; j < 25; ++j)
                P[j] = pf[r * 133 + dl * 25 + j] + b2[50 * de + j];
            float o, l;
            rqs(P, xv, o, l);
            out[(size_t)rowg * DDIM + 2 * de] = o;
            ldsum += l;
        }
        if (t < 64) {
            int de = bx * 5 + 4;
            if (de < 64) {                        // bx=12 has only 4 de
                float xv = x[(size_t)rowg * DDIM + 2 * de];
                float P[25];
                #pragma unroll
                for (int j = 0; j < 25; ++j)
                    P[j] = pf[r * 133 + 4 * 25 + j] + b2[50 * de + j];
                float o, l;
                rqs(P, xv, o, l);
                out[(size_t)rowg * DDIM + 2 * de] = o;
                ldsum += l;
            }
        }
        atomicAdd(&logdet[rowg], ldsum);
    }
}

extern "C" void kernel_launch(void* const* d_in, const int* in_sizes, int n_in,
                              void* d_out, int out_size, void* d_ws, size_t ws_size,
                              hipStream_t stream) {
    const float* x  = (const float*)d_in[0];
    // d_in[1] = mask — structure (d%2) hardcoded
    const float* W1 = (const float*)d_in[2];
    const float* b1 = (const float*)d_in[3];
    const float* W2 = (const float*)d_in[4];
    const float* b2 = (const float*)d_in[5];

    float* out    = (float*)d_out;                          // [B, D]
    float* logdet = (float*)d_out + (size_t)B_ROWS * DDIM;  // [B]

    _Float16* hid_hi = (_Float16*)d_ws;                     // 16 MB
    _Float16* hid_lo = hid_hi + (size_t)B_ROWS * HDIM;      // 16 MB
    _Float16* w2t_hi = hid_lo + (size_t)B_ROWS * HDIM;      // 852 KB
    _Float16* w2t_lo = w2t_hi + (size_t)NPACK * HDIM;       // 852 KB

    k3_w2split<<<dim3(NPACK * 32 / 256), dim3(256), 0, stream>>>(W2, w2t_hi, w2t_lo);
    k1_hidden <<<dim3(B_ROWS / 32),      dim3(256), 0, stream>>>(x, W1, b1, hid_hi, hid_lo, out, logdet);
    k2_mfma   <<<dim3(13, B_ROWS / 128), dim3(256), 0, stream>>>(
        x, hid_hi, hid_lo, w2t_hi, w2t_lo, b2, out, logdet);
}